// Round 1
// baseline (1269.116 us; speedup 1.0000x reference)
//
#include <hip/hip_runtime.h>
#include <cstdint>

#define N_TOTAL 10000
#define D 128
#define FEAT 3072
#define BS_BN 100
#define TOPK 50

// ---------------- K1: x = in @ W1^T, split-K atomic ----------------
// grid (79, 4), block 256. M-tile 128 rows, N = 128 cols, K-slice 768, k-step 32.
__global__ __launch_bounds__(256) void k_gemm1(const float* __restrict__ in,
                                               const float* __restrict__ W1,
                                               float* __restrict__ x) {
  __shared__ float As[32][132];  // [k][row]
  __shared__ float Bs[32][132];  // [k][col]
  const int t = threadIdx.x;
  const int row0 = blockIdx.x * 128;
  const int k0 = blockIdx.y * 768;
  const int ty = t >> 4, tx = t & 15;
  const int i0 = ty * 8, j0 = tx * 8;
  float acc[8][8];
#pragma unroll
  for (int r = 0; r < 8; ++r)
#pragma unroll
    for (int c = 0; c < 8; ++c) acc[r][c] = 0.f;

  for (int kb = 0; kb < 768; kb += 32) {
    __syncthreads();
#pragma unroll
    for (int q = 0; q < 4; ++q) {
      int f = t + 256 * q;
      int row = f >> 3, kq = f & 7;
      int grow = row0 + row; if (grow >= N_TOTAL) grow = N_TOTAL - 1;
      float4 av = *(const float4*)(in + (size_t)grow * FEAT + k0 + kb + kq * 4);
      As[kq * 4 + 0][row] = av.x; As[kq * 4 + 1][row] = av.y;
      As[kq * 4 + 2][row] = av.z; As[kq * 4 + 3][row] = av.w;
      float4 bv = *(const float4*)(W1 + (size_t)row * FEAT + k0 + kb + kq * 4);
      Bs[kq * 4 + 0][row] = bv.x; Bs[kq * 4 + 1][row] = bv.y;
      Bs[kq * 4 + 2][row] = bv.z; Bs[kq * 4 + 3][row] = bv.w;
    }
    __syncthreads();
#pragma unroll
    for (int kk = 0; kk < 32; ++kk) {
      float4 a0 = *(const float4*)&As[kk][i0];
      float4 a1 = *(const float4*)&As[kk][i0 + 4];
      float4 b0 = *(const float4*)&Bs[kk][j0];
      float4 b1 = *(const float4*)&Bs[kk][j0 + 4];
      float av[8] = {a0.x, a0.y, a0.z, a0.w, a1.x, a1.y, a1.z, a1.w};
      float bv[8] = {b0.x, b0.y, b0.z, b0.w, b1.x, b1.y, b1.z, b1.w};
#pragma unroll
      for (int r = 0; r < 8; ++r)
#pragma unroll
        for (int c = 0; c < 8; ++c) acc[r][c] = fmaf(av[r], bv[c], acc[r][c]);
    }
  }
#pragma unroll
  for (int r = 0; r < 8; ++r) {
    int gi = row0 + i0 + r;
    if (gi < N_TOTAL) {
#pragma unroll
      for (int c = 0; c < 8; ++c)
        atomicAdd(&x[(size_t)gi * D + j0 + c], acc[r][c]);
    }
  }
}

// ---------------- K2: BatchNorm per 100-row batch ----------------
// grid 100, block 128 (thread = channel)
__global__ __launch_bounds__(128) void k_bn(const float* __restrict__ x,
                                            const float* __restrict__ b1,
                                            const float* __restrict__ gamma,
                                            const float* __restrict__ beta,
                                            const float* __restrict__ sw,
                                            float* __restrict__ out_final,
                                            float* __restrict__ outf,
                                            float* __restrict__ wsw) {
  const int b = blockIdx.x, c = threadIdx.x;
  const float bias = b1[c];
  float s = 0.f, s2 = 0.f;
  const float* xp = x + (size_t)b * BS_BN * D + c;
  for (int r = 0; r < BS_BN; ++r) {
    float v = xp[(size_t)r * D] + bias;
    s += v; s2 = fmaf(v, v, s2);
  }
  float mean = s * (1.f / BS_BN);
  float var = s2 * (1.f / BS_BN) - mean * mean;
  float scale = gamma[c] * rsqrtf(var + 1e-5f);
  float shift = beta[c] - mean * scale;
  float swc = sw[c];
  float* op  = out_final + (size_t)b * BS_BN * D + c;
  float* ofp = outf + (size_t)b * BS_BN * D + c;
  float* wp  = wsw + (size_t)b * BS_BN * D + c;
  for (int r = 0; r < BS_BN; ++r) {
    float v = fmaf(xp[(size_t)r * D] + bias, scale, shift);
    op[(size_t)r * D] = v;
    ofp[(size_t)r * D] = v;
    wp[(size_t)r * D] = v * swc;
  }
}

// ---------------- K2b: a[i] = sum_k sw[k]*out[i,k]^2 ----------------
// grid 2500, block 256 (one wave per row)
__global__ __launch_bounds__(256) void k_arow(const float* __restrict__ outf,
                                              const float* __restrict__ sw,
                                              float* __restrict__ aarr) {
  const int t = threadIdx.x;
  const int lane = t & 63;
  const int row = blockIdx.x * 4 + (t >> 6);
  float o1 = outf[(size_t)row * D + lane];
  float o2 = outf[(size_t)row * D + 64 + lane];
  float v = sw[lane] * o1 * o1 + sw[64 + lane] * o2 * o2;
#pragma unroll
  for (int off = 32; off >= 1; off >>= 1) v += __shfl_xor(v, off);
  if (lane == 0) aarr[row] = v;
}

// ---------------- K3: scores = relu(a_i + a_j + sb - 2*out_i . wsw_j) ----------------
// grid (79,79), block 256. 128x128 tile, K=128, k-step 32. Writes S in-place in d_out.
__global__ __launch_bounds__(256) void k_score(const float* __restrict__ outf,
                                               const float* __restrict__ wsw,
                                               const float* __restrict__ aarr,
                                               const float* __restrict__ sbp,
                                               float* __restrict__ S) {
  __shared__ float As[32][132];
  __shared__ float Bs[32][132];
  const int t = threadIdx.x;
  const int ib = blockIdx.x * 128;
  const int jb = blockIdx.y * 128;
  const int ty = t >> 4, tx = t & 15;
  const int i0 = ty * 8, j0 = tx * 8;
  float acc[8][8];
#pragma unroll
  for (int r = 0; r < 8; ++r)
#pragma unroll
    for (int c = 0; c < 8; ++c) acc[r][c] = 0.f;

  for (int kb = 0; kb < 128; kb += 32) {
    __syncthreads();
#pragma unroll
    for (int q = 0; q < 4; ++q) {
      int f = t + 256 * q;
      int row = f >> 3, kq = f & 7;
      int gi = ib + row; if (gi >= N_TOTAL) gi = N_TOTAL - 1;
      int gj = jb + row; if (gj >= N_TOTAL) gj = N_TOTAL - 1;
      float4 av = *(const float4*)(outf + (size_t)gi * D + kb + kq * 4);
      float4 bv = *(const float4*)(wsw + (size_t)gj * D + kb + kq * 4);
      As[kq * 4 + 0][row] = av.x; As[kq * 4 + 1][row] = av.y;
      As[kq * 4 + 2][row] = av.z; As[kq * 4 + 3][row] = av.w;
      Bs[kq * 4 + 0][row] = bv.x; Bs[kq * 4 + 1][row] = bv.y;
      Bs[kq * 4 + 2][row] = bv.z; Bs[kq * 4 + 3][row] = bv.w;
    }
    __syncthreads();
#pragma unroll
    for (int kk = 0; kk < 32; ++kk) {
      float4 a0 = *(const float4*)&As[kk][i0];
      float4 a1 = *(const float4*)&As[kk][i0 + 4];
      float4 b0 = *(const float4*)&Bs[kk][j0];
      float4 b1 = *(const float4*)&Bs[kk][j0 + 4];
      float av[8] = {a0.x, a0.y, a0.z, a0.w, a1.x, a1.y, a1.z, a1.w};
      float bv[8] = {b0.x, b0.y, b0.z, b0.w, b1.x, b1.y, b1.z, b1.w};
#pragma unroll
      for (int r = 0; r < 8; ++r)
#pragma unroll
        for (int c = 0; c < 8; ++c) acc[r][c] = fmaf(av[r], bv[c], acc[r][c]);
    }
  }
  const float sb = sbp[0];
  float aJ[8];
#pragma unroll
  for (int c = 0; c < 8; ++c) {
    int gj = jb + j0 + c;
    aJ[c] = aarr[gj < N_TOTAL ? gj : N_TOTAL - 1];
  }
#pragma unroll
  for (int r = 0; r < 8; ++r) {
    int gi = ib + i0 + r;
    if (gi >= N_TOTAL) continue;
    float ai = aarr[gi] + sb;
    float o[8];
#pragma unroll
    for (int c = 0; c < 8; ++c) {
      float s = ai + aJ[c] - 2.f * acc[r][c];
      o[c] = (s > 0.f) ? s : 0.f;   // +0.0 always (uint-monotone for top-k kernel)
    }
    if (jb + j0 < N_TOTAL) {  // 10000 % 8 == 0: 8-col group is all-in or all-out
      *(float4*)(S + (size_t)gi * N_TOTAL + jb + j0)     = make_float4(o[0], o[1], o[2], o[3]);
      *(float4*)(S + (size_t)gi * N_TOTAL + jb + j0 + 4) = make_float4(o[4], o[5], o[6], o[7]);
    }
  }
}

// ---------------- K5: per-row exact top-50 + softmax + scatter (in-place) ----------------
// grid 10000, block 256. Row in registers (40/thread); binary search on uint bits.
__global__ __launch_bounds__(256) void k_topk(float* __restrict__ S) {
  const int t = threadIdx.x;
  const int lane = t & 63;
  const int wid = t >> 6;
  const size_t rbase = (size_t)blockIdx.x * N_TOTAL;
  const uint32_t* rp = (const uint32_t*)(S + rbase);
  uint32_t v[40];
#pragma unroll
  for (int j = 0; j < 40; ++j) {
    int col = j * 256 + t;
    v[j] = (col < N_TOTAL) ? rp[col] : 0u;  // pad with +0.0 (handled by idx-tiebreak)
  }
  __shared__ int wcnt[4];
  __shared__ float topv[TOPK];
  __shared__ int topi[TOPK];
  __shared__ int ctr;

  // f(M) = #{v >= M}. Find T = 50th largest: f(T) >= 50, f(T+1) < 50.
  uint32_t L = 0u, H = 0x7F800000u;  // scores finite & >= +0.0
  while (H - L > 1u) {
    uint32_t M = L + ((H - L) >> 1);
    int c = 0;
#pragma unroll
    for (int j = 0; j < 40; ++j) c += (v[j] >= M) ? 1 : 0;
#pragma unroll
    for (int off = 32; off >= 1; off >>= 1) c += __shfl_xor(c, off);
    if (lane == 0) wcnt[wid] = c;
    __syncthreads();
    int f = wcnt[0] + wcnt[1] + wcnt[2] + wcnt[3];
    __syncthreads();
    if (f >= TOPK) L = M; else H = M;
  }
  const uint32_t T = L;

  int cg = 0;
#pragma unroll
  for (int j = 0; j < 40; ++j) cg += (v[j] > T) ? 1 : 0;
#pragma unroll
  for (int off = 32; off >= 1; off >>= 1) cg += __shfl_xor(cg, off);
  if (lane == 0) wcnt[wid] = cg;
  if (t == 0) ctr = 0;
  __syncthreads();
  const int cnt_gt = wcnt[0] + wcnt[1] + wcnt[2] + wcnt[3];  // <= 49
  __syncthreads();

  // collect strict-greater (order irrelevant: softmax+scatter are permutation-invariant)
#pragma unroll
  for (int j = 0; j < 40; ++j) {
    if (v[j] > T) {
      int p = atomicAdd(&ctr, 1);
      topv[p] = __uint_as_float(v[j]);
      topi[p] = j * 256 + t;
    }
  }
  __syncthreads();

  // equals: take (50 - cnt_gt) smallest indices (matches jax.lax.top_k tie-break)
  int remaining = TOPK - cnt_gt;
  int base = cnt_gt;
  for (int j = 0; j < 40; ++j) {
    bool eq = (v[j] == T) && (j * 256 + t < N_TOTAL);
    unsigned long long m = __ballot(eq);
    int wsum = __popcll(m);
    int wrank = __popcll(m & ((1ull << lane) - 1ull));
    if (lane == 0) wcnt[wid] = wsum;
    __syncthreads();
    int pre = 0;
#pragma unroll
    for (int w = 0; w < 4; ++w) if (w < wid) pre += wcnt[w];
    int tot = wcnt[0] + wcnt[1] + wcnt[2] + wcnt[3];
    int grank = pre + wrank;
    if (eq && grank < remaining) {
      topv[base + grank] = __uint_as_float(T);
      topi[base + grank] = j * 256 + t;
    }
    int take = (tot < remaining) ? tot : remaining;
    base += take;
    remaining -= take;
    __syncthreads();
    if (remaining == 0) break;  // uniform
  }

  // softmax over the 50 (wave 0)
  if (wid == 0) {
    float xv = (lane < TOPK) ? topv[lane] : -1e30f;
    float mx = xv;
#pragma unroll
    for (int off = 32; off >= 1; off >>= 1) mx = fmaxf(mx, __shfl_xor(mx, off));
    float e = (lane < TOPK) ? expf(xv - mx) : 0.f;
    float ss = e;
#pragma unroll
    for (int off = 32; off >= 1; off >>= 1) ss += __shfl_xor(ss, off);
    if (lane < TOPK) topv[lane] = e / ss;
  }
  __syncthreads();

  // rewrite row: zeros + scatter (barrier drains stores -> ordered)
  float4 z = make_float4(0.f, 0.f, 0.f, 0.f);
  float4* rp4 = (float4*)(S + rbase);
  for (int i = t; i < N_TOTAL / 4; i += 256) rp4[i] = z;
  __syncthreads();
  if (t < TOPK) S[rbase + topi[t]] = topv[t];
}

extern "C" void kernel_launch(void* const* d_in, const int* in_sizes, int n_in,
                              void* d_out, int out_size, void* d_ws, size_t ws_size,
                              hipStream_t stream) {
  const float* in    = (const float*)d_in[0];
  const float* W1    = (const float*)d_in[1];
  const float* b1    = (const float*)d_in[2];
  const float* gamma = (const float*)d_in[3];
  const float* beta  = (const float*)d_in[4];
  const float* sw    = (const float*)d_in[5];
  const float* sb    = (const float*)d_in[6];
  float* out_f = (float*)d_out;
  float* S = out_f + (size_t)N_TOTAL * D;  // [10000,10000]

  float* wsf  = (float*)d_ws;
  float* x    = wsf;                // 1,280,000 f
  float* outf = wsf + 1280000;      // 1,280,000 f
  float* wswb = wsf + 2560000;      // 1,280,000 f
  float* aarr = wsf + 3840000;      // 10,000 f   (total ~15.4 MB of ws)

  hipMemsetAsync(x, 0, (size_t)N_TOTAL * D * sizeof(float), stream);
  k_gemm1<<<dim3(79, 4), 256, 0, stream>>>(in, W1, x);
  k_bn<<<100, 128, 0, stream>>>(x, b1, gamma, beta, sw, out_f, outf, wswb);
  k_arow<<<2500, 256, 0, stream>>>(outf, sw, aarr);
  k_score<<<dim3(79, 79), 256, 0, stream>>>(outf, wswb, aarr, sb, S);
  k_topk<<<10000, 256, 0, stream>>>(S);
}

// Round 5
// 1168.278 us; speedup vs baseline: 1.0863x; 1.0863x over previous
//
#include <hip/hip_runtime.h>
#include <cstdint>

#define N_TOTAL 10000
#define D 128
#define FEAT 3072
#define BS_BN 100
#define TOPK 50

typedef unsigned int uint;
typedef short short8 __attribute__((ext_vector_type(8)));
typedef float f32x4 __attribute__((ext_vector_type(4)));
union U16 { uint4 u; short8 b; };

// Split fp32 -> bf16 hi (truncate) + bf16 lo (truncate of residual), 8 at a time.
__device__ inline void split8(float4 f0, float4 f1, U16& h, U16& l) {
  float f[8] = {f0.x, f0.y, f0.z, f0.w, f1.x, f1.y, f1.z, f1.w};
  uint hb[8], lb[8];
#pragma unroll
  for (int e = 0; e < 8; ++e) {
    uint b = __float_as_uint(f[e]);
    uint hx = b & 0xFFFF0000u;
    float lf = f[e] - __uint_as_float(hx);
    hb[e] = b >> 16;
    lb[e] = __float_as_uint(lf) >> 16;
  }
  h.u = make_uint4(hb[0] | (hb[1] << 16), hb[2] | (hb[3] << 16),
                   hb[4] | (hb[5] << 16), hb[6] | (hb[7] << 16));
  l.u = make_uint4(lb[0] | (lb[1] << 16), lb[2] | (lb[3] << 16),
                   lb[4] | (lb[5] << 16), lb[6] | (lb[7] << 16));
}

// ---------------- K1: x = in @ W1^T, split-K atomic (ROUND-1 proven, fp32) ----------------
__global__ __launch_bounds__(256) void k_gemm1(const float* __restrict__ in,
                                               const float* __restrict__ W1,
                                               float* __restrict__ x) {
  __shared__ float As[32][132];
  __shared__ float Bs[32][132];
  const int t = threadIdx.x;
  const int row0 = blockIdx.x * 128;
  const int k0 = blockIdx.y * 768;
  const int ty = t >> 4, tx = t & 15;
  const int i0 = ty * 8, j0 = tx * 8;
  float acc[8][8];
#pragma unroll
  for (int r = 0; r < 8; ++r)
#pragma unroll
    for (int c = 0; c < 8; ++c) acc[r][c] = 0.f;

  for (int kb = 0; kb < 768; kb += 32) {
    __syncthreads();
#pragma unroll
    for (int q = 0; q < 4; ++q) {
      int f = t + 256 * q;
      int row = f >> 3, kq = f & 7;
      int grow = row0 + row; if (grow >= N_TOTAL) grow = N_TOTAL - 1;
      float4 av = *(const float4*)(in + (size_t)grow * FEAT + k0 + kb + kq * 4);
      As[kq * 4 + 0][row] = av.x; As[kq * 4 + 1][row] = av.y;
      As[kq * 4 + 2][row] = av.z; As[kq * 4 + 3][row] = av.w;
      float4 bv = *(const float4*)(W1 + (size_t)row * FEAT + k0 + kb + kq * 4);
      Bs[kq * 4 + 0][row] = bv.x; Bs[kq * 4 + 1][row] = bv.y;
      Bs[kq * 4 + 2][row] = bv.z; Bs[kq * 4 + 3][row] = bv.w;
    }
    __syncthreads();
#pragma unroll
    for (int kk = 0; kk < 32; ++kk) {
      float4 a0 = *(const float4*)&As[kk][i0];
      float4 a1 = *(const float4*)&As[kk][i0 + 4];
      float4 b0 = *(const float4*)&Bs[kk][j0];
      float4 b1 = *(const float4*)&Bs[kk][j0 + 4];
      float av[8] = {a0.x, a0.y, a0.z, a0.w, a1.x, a1.y, a1.z, a1.w};
      float bv[8] = {b0.x, b0.y, b0.z, b0.w, b1.x, b1.y, b1.z, b1.w};
#pragma unroll
      for (int r = 0; r < 8; ++r)
#pragma unroll
        for (int c = 0; c < 8; ++c) acc[r][c] = fmaf(av[r], bv[c], acc[r][c]);
    }
  }
#pragma unroll
  for (int r = 0; r < 8; ++r) {
    int gi = row0 + i0 + r;
    if (gi < N_TOTAL) {
#pragma unroll
      for (int c = 0; c < 8; ++c)
        atomicAdd(&x[(size_t)gi * D + j0 + c], acc[r][c]);
    }
  }
}

// ---------------- K2: BatchNorm per 100-row batch (ROUND-1 proven) ----------------
__global__ __launch_bounds__(128) void k_bn(const float* __restrict__ x,
                                            const float* __restrict__ b1,
                                            const float* __restrict__ gamma,
                                            const float* __restrict__ beta,
                                            const float* __restrict__ sw,
                                            float* __restrict__ out_final,
                                            float* __restrict__ outf,
                                            float* __restrict__ wsw) {
  const int b = blockIdx.x, c = threadIdx.x;
  const float bias = b1[c];
  float s = 0.f, s2 = 0.f;
  const float* xp = x + (size_t)b * BS_BN * D + c;
  for (int r = 0; r < BS_BN; ++r) {
    float v = xp[(size_t)r * D] + bias;
    s += v; s2 = fmaf(v, v, s2);
  }
  float mean = s * (1.f / BS_BN);
  float var = s2 * (1.f / BS_BN) - mean * mean;
  float scale = gamma[c] * rsqrtf(var + 1e-5f);
  float shift = beta[c] - mean * scale;
  float swc = sw[c];
  float* op  = out_final + (size_t)b * BS_BN * D + c;
  float* ofp = outf + (size_t)b * BS_BN * D + c;
  float* wp  = wsw + (size_t)b * BS_BN * D + c;
  for (int r = 0; r < BS_BN; ++r) {
    float v = fmaf(xp[(size_t)r * D] + bias, scale, shift);
    op[(size_t)r * D] = v;
    ofp[(size_t)r * D] = v;
    wp[(size_t)r * D] = v * swc;
  }
}

// ---------------- K2b: a[i] = sum_k sw[k]*out[i,k]^2 (ROUND-1 proven) ----------------
__global__ __launch_bounds__(256) void k_arow(const float* __restrict__ outf,
                                              const float* __restrict__ sw,
                                              float* __restrict__ aarr) {
  const int t = threadIdx.x;
  const int lane = t & 63;
  const int row = blockIdx.x * 4 + (t >> 6);
  float o1 = outf[(size_t)row * D + lane];
  float o2 = outf[(size_t)row * D + 64 + lane];
  float v = sw[lane] * o1 * o1 + sw[64 + lane] * o2 * o2;
#pragma unroll
  for (int off = 32; off >= 1; off >>= 1) v += __shfl_xor(v, off);
  if (lane == 0) aarr[row] = v;
}

// ---------------- K3: scores via split-bf16 MFMA (fp32 staging, in-register split) ----------------
// grid (79,79), block 256 = 4 waves (2x2 quadrants of 64x64). K=128, kstep 32.
// ONLY changed kernel this round vs round 1: fp32 LDS tiles (round-1-style memory
// pattern), split to bf16 hi/lo at fragment-read time, 3x mfma_16x16x32_bf16.
__global__ __launch_bounds__(256) void k_score(const float* __restrict__ outf,
                                               const float* __restrict__ wsw,
                                               const float* __restrict__ aarr,
                                               const float* __restrict__ sbp,
                                               float* __restrict__ S) {
  __shared__ alignas(16) float Af[128 * 44];  // [row][k] pad 32->44 (16B-mult stride)
  __shared__ alignas(16) float Bf[128 * 44];
  const int t = threadIdx.x;
  const int lane = t & 63, wid = t >> 6;
  const int q = lane >> 4, l15 = lane & 15;
  const int ib = blockIdx.x * 128, jb = blockIdx.y * 128;
  const int wm = (wid & 1) * 64, wn = (wid >> 1) * 64;

  f32x4 acc[4][4];
#pragma unroll
  for (int mt = 0; mt < 4; ++mt)
#pragma unroll
    for (int nt = 0; nt < 4; ++nt) acc[mt][nt] = (f32x4){0.f, 0.f, 0.f, 0.f};

  for (int kb = 0; kb < D; kb += 32) {
    __syncthreads();
#pragma unroll
    for (int s = 0; s < 4; ++s) {
      int idx = t + 256 * s;              // 0..1023 float4 slots per matrix
      int row = idx >> 3, f4 = (idx & 7) * 4;
      int gi = ib + row; if (gi > N_TOTAL - 1) gi = N_TOTAL - 1;
      int gj = jb + row; if (gj > N_TOTAL - 1) gj = N_TOTAL - 1;
      *(float4*)&Af[row * 44 + f4] = *(const float4*)&outf[(size_t)gi * D + kb + f4];
      *(float4*)&Bf[row * 44 + f4] = *(const float4*)&wsw[(size_t)gj * D + kb + f4];
    }
    __syncthreads();
    U16 Ah[4], Al[4], Bh[4], Bl[4];
#pragma unroll
    for (int mt = 0; mt < 4; ++mt) {
      int ro = (wm + mt * 16 + l15) * 44 + q * 8;
      float4 x0 = *(const float4*)&Af[ro];
      float4 x1 = *(const float4*)&Af[ro + 4];
      split8(x0, x1, Ah[mt], Al[mt]);
    }
#pragma unroll
    for (int nt = 0; nt < 4; ++nt) {
      int ro = (wn + nt * 16 + l15) * 44 + q * 8;
      float4 x0 = *(const float4*)&Bf[ro];
      float4 x1 = *(const float4*)&Bf[ro + 4];
      split8(x0, x1, Bh[nt], Bl[nt]);
    }
#pragma unroll
    for (int mt = 0; mt < 4; ++mt)
#pragma unroll
      for (int nt = 0; nt < 4; ++nt) {
        acc[mt][nt] = __builtin_amdgcn_mfma_f32_16x16x32_bf16(Ah[mt].b, Bh[nt].b, acc[mt][nt], 0, 0, 0);
        acc[mt][nt] = __builtin_amdgcn_mfma_f32_16x16x32_bf16(Ah[mt].b, Bl[nt].b, acc[mt][nt], 0, 0, 0);
        acc[mt][nt] = __builtin_amdgcn_mfma_f32_16x16x32_bf16(Al[mt].b, Bh[nt].b, acc[mt][nt], 0, 0, 0);
      }
  }

  // C/D layout (16x16x32): col = lane&15, row = (lane>>4)*4 + reg
  const float sb = sbp[0];
  float ajv[4];
  int gjc[4];
#pragma unroll
  for (int nt = 0; nt < 4; ++nt) {
    gjc[nt] = jb + wn + nt * 16 + l15;
    ajv[nt] = aarr[gjc[nt] < N_TOTAL ? gjc[nt] : N_TOTAL - 1];
  }
#pragma unroll
  for (int mt = 0; mt < 4; ++mt) {
#pragma unroll
    for (int r = 0; r < 4; ++r) {
      int gi = ib + wm + mt * 16 + q * 4 + r;
      if (gi >= N_TOTAL) continue;
      float ai = aarr[gi] + sb;
#pragma unroll
      for (int nt = 0; nt < 4; ++nt) {
        if (gjc[nt] < N_TOTAL) {
          float s = ai + ajv[nt] - 2.f * acc[mt][nt][r];
          S[(size_t)gi * N_TOTAL + gjc[nt]] = (s > 0.f) ? s : 0.f;  // +0.0 always
        }
      }
    }
  }
}

// ---------------- K5: per-row exact top-50 + softmax + scatter (ROUND-1 proven) ----------------
__global__ __launch_bounds__(256) void k_topk(float* __restrict__ S) {
  const int t = threadIdx.x;
  const int lane = t & 63;
  const int wid = t >> 6;
  const size_t rbase = (size_t)blockIdx.x * N_TOTAL;
  const uint32_t* rp = (const uint32_t*)(S + rbase);
  uint32_t v[40];
#pragma unroll
  for (int j = 0; j < 40; ++j) {
    int col = j * 256 + t;
    v[j] = (col < N_TOTAL) ? rp[col] : 0u;
  }
  __shared__ int wcnt[4];
  __shared__ float topv[TOPK];
  __shared__ int topi[TOPK];
  __shared__ int ctr;

  uint32_t L = 0u, H = 0x7F800000u;
  while (H - L > 1u) {
    uint32_t M = L + ((H - L) >> 1);
    int c = 0;
#pragma unroll
    for (int j = 0; j < 40; ++j) c += (v[j] >= M) ? 1 : 0;
#pragma unroll
    for (int off = 32; off >= 1; off >>= 1) c += __shfl_xor(c, off);
    if (lane == 0) wcnt[wid] = c;
    __syncthreads();
    int f = wcnt[0] + wcnt[1] + wcnt[2] + wcnt[3];
    __syncthreads();
    if (f >= TOPK) L = M; else H = M;
  }
  const uint32_t T = L;

  int cg = 0;
#pragma unroll
  for (int j = 0; j < 40; ++j) cg += (v[j] > T) ? 1 : 0;
#pragma unroll
  for (int off = 32; off >= 1; off >>= 1) cg += __shfl_xor(cg, off);
  if (lane == 0) wcnt[wid] = cg;
  if (t == 0) ctr = 0;
  __syncthreads();
  const int cnt_gt = wcnt[0] + wcnt[1] + wcnt[2] + wcnt[3];
  __syncthreads();

#pragma unroll
  for (int j = 0; j < 40; ++j) {
    if (v[j] > T) {
      int p = atomicAdd(&ctr, 1);
      topv[p] = __uint_as_float(v[j]);
      topi[p] = j * 256 + t;
    }
  }
  __syncthreads();

  int remaining = TOPK - cnt_gt;
  int base = cnt_gt;
  for (int j = 0; j < 40; ++j) {
    bool eq = (v[j] == T) && (j * 256 + t < N_TOTAL);
    unsigned long long m = __ballot(eq);
    int wsum = __popcll(m);
    int wrank = __popcll(m & ((1ull << lane) - 1ull));
    if (lane == 0) wcnt[wid] = wsum;
    __syncthreads();
    int pre = 0;
#pragma unroll
    for (int w = 0; w < 4; ++w) if (w < wid) pre += wcnt[w];
    int tot = wcnt[0] + wcnt[1] + wcnt[2] + wcnt[3];
    int grank = pre + wrank;
    if (eq && grank < remaining) {
      topv[base + grank] = __uint_as_float(T);
      topi[base + grank] = j * 256 + t;
    }
    int take = (tot < remaining) ? tot : remaining;
    base += take;
    remaining -= take;
    __syncthreads();
    if (remaining == 0) break;
  }

  if (wid == 0) {
    float xv = (lane < TOPK) ? topv[lane] : -1e30f;
    float mx = xv;
#pragma unroll
    for (int off = 32; off >= 1; off >>= 1) mx = fmaxf(mx, __shfl_xor(mx, off));
    float e = (lane < TOPK) ? expf(xv - mx) : 0.f;
    float ss = e;
#pragma unroll
    for (int off = 32; off >= 1; off >>= 1) ss += __shfl_xor(ss, off);
    if (lane < TOPK) topv[lane] = e / ss;
  }
  __syncthreads();

  float4 z = make_float4(0.f, 0.f, 0.f, 0.f);
  float4* rp4 = (float4*)(S + rbase);
  for (int i = t; i < N_TOTAL / 4; i += 256) rp4[i] = z;
  __syncthreads();
  if (t < TOPK) S[rbase + topi[t]] = topv[t];
}

extern "C" void kernel_launch(void* const* d_in, const int* in_sizes, int n_in,
                              void* d_out, int out_size, void* d_ws, size_t ws_size,
                              hipStream_t stream) {
  const float* in    = (const float*)d_in[0];
  const float* W1    = (const float*)d_in[1];
  const float* b1    = (const float*)d_in[2];
  const float* gamma = (const float*)d_in[3];
  const float* beta  = (const float*)d_in[4];
  const float* sw    = (const float*)d_in[5];
  const float* sb    = (const float*)d_in[6];
  float* out_f = (float*)d_out;
  float* S = out_f + (size_t)N_TOTAL * D;  // [10000,10000]

  // ROUND-1 proven ws layout (~15.4 MB)
  float* wsf  = (float*)d_ws;
  float* x    = wsf;                // 1,280,000 f
  float* outf = wsf + 1280000;      // 1,280,000 f
  float* wswb = wsf + 2560000;      // 1,280,000 f
  float* aarr = wsf + 3840000;      // 10,000 f

  hipMemsetAsync(x, 0, (size_t)N_TOTAL * D * sizeof(float), stream);
  k_gemm1<<<dim3(79, 4), 256, 0, stream>>>(in, W1, x);
  k_bn<<<100, 128, 0, stream>>>(x, b1, gamma, beta, sw, out_f, outf, wswb);
  k_arow<<<2500, 256, 0, stream>>>(outf, sw, aarr);
  k_score<<<dim3(79, 79), 256, 0, stream>>>(outf, wswb, aarr, sb, S);
  k_topk<<<10000, 256, 0, stream>>>(S);
}

// Round 6
// 1029.533 us; speedup vs baseline: 1.2327x; 1.1348x over previous
//
#include <hip/hip_runtime.h>
#include <cstdint>

#define N_TOTAL 10000
#define D 128
#define FEAT 3072
#define BS_BN 100
#define TOPK 50

typedef unsigned int uint;
typedef short short8 __attribute__((ext_vector_type(8)));
typedef float f32x4 __attribute__((ext_vector_type(4)));
union U16 { uint4 u; short8 b; };

// Split fp32 -> bf16 hi (truncate) + bf16 lo (truncate of residual), 8 at a time.
__device__ inline void split8(float4 f0, float4 f1, U16& h, U16& l) {
  float f[8] = {f0.x, f0.y, f0.z, f0.w, f1.x, f1.y, f1.z, f1.w};
  uint hb[8], lb[8];
#pragma unroll
  for (int e = 0; e < 8; ++e) {
    uint b = __float_as_uint(f[e]);
    uint hx = b & 0xFFFF0000u;
    float lf = f[e] - __uint_as_float(hx);
    hb[e] = b >> 16;
    lb[e] = __float_as_uint(lf) >> 16;
  }
  h.u = make_uint4(hb[0] | (hb[1] << 16), hb[2] | (hb[3] << 16),
                   hb[4] | (hb[5] << 16), hb[6] | (hb[7] << 16));
  l.u = make_uint4(lb[0] | (lb[1] << 16), lb[2] | (lb[3] << 16),
                   lb[4] | (lb[5] << 16), lb[6] | (lb[7] << 16));
}

// ---------------- K1: x = in @ W1^T, split-K atomic (ROUND-1 proven, fp32) ----------------
__global__ __launch_bounds__(256) void k_gemm1(const float* __restrict__ in,
                                               const float* __restrict__ W1,
                                               float* __restrict__ x) {
  __shared__ float As[32][132];
  __shared__ float Bs[32][132];
  const int t = threadIdx.x;
  const int row0 = blockIdx.x * 128;
  const int k0 = blockIdx.y * 768;
  const int ty = t >> 4, tx = t & 15;
  const int i0 = ty * 8, j0 = tx * 8;
  float acc[8][8];
#pragma unroll
  for (int r = 0; r < 8; ++r)
#pragma unroll
    for (int c = 0; c < 8; ++c) acc[r][c] = 0.f;

  for (int kb = 0; kb < 768; kb += 32) {
    __syncthreads();
#pragma unroll
    for (int q = 0; q < 4; ++q) {
      int f = t + 256 * q;
      int row = f >> 3, kq = f & 7;
      int grow = row0 + row; if (grow >= N_TOTAL) grow = N_TOTAL - 1;
      float4 av = *(const float4*)(in + (size_t)grow * FEAT + k0 + kb + kq * 4);
      As[kq * 4 + 0][row] = av.x; As[kq * 4 + 1][row] = av.y;
      As[kq * 4 + 2][row] = av.z; As[kq * 4 + 3][row] = av.w;
      float4 bv = *(const float4*)(W1 + (size_t)row * FEAT + k0 + kb + kq * 4);
      Bs[kq * 4 + 0][row] = bv.x; Bs[kq * 4 + 1][row] = bv.y;
      Bs[kq * 4 + 2][row] = bv.z; Bs[kq * 4 + 3][row] = bv.w;
    }
    __syncthreads();
#pragma unroll
    for (int kk = 0; kk < 32; ++kk) {
      float4 a0 = *(const float4*)&As[kk][i0];
      float4 a1 = *(const float4*)&As[kk][i0 + 4];
      float4 b0 = *(const float4*)&Bs[kk][j0];
      float4 b1 = *(const float4*)&Bs[kk][j0 + 4];
      float av[8] = {a0.x, a0.y, a0.z, a0.w, a1.x, a1.y, a1.z, a1.w};
      float bv[8] = {b0.x, b0.y, b0.z, b0.w, b1.x, b1.y, b1.z, b1.w};
#pragma unroll
      for (int r = 0; r < 8; ++r)
#pragma unroll
        for (int c = 0; c < 8; ++c) acc[r][c] = fmaf(av[r], bv[c], acc[r][c]);
    }
  }
#pragma unroll
  for (int r = 0; r < 8; ++r) {
    int gi = row0 + i0 + r;
    if (gi < N_TOTAL) {
#pragma unroll
      for (int c = 0; c < 8; ++c)
        atomicAdd(&x[(size_t)gi * D + j0 + c], acc[r][c]);
    }
  }
}

// ---------------- K2: BatchNorm per 100-row batch (ROUND-1 proven) ----------------
__global__ __launch_bounds__(128) void k_bn(const float* __restrict__ x,
                                            const float* __restrict__ b1,
                                            const float* __restrict__ gamma,
                                            const float* __restrict__ beta,
                                            const float* __restrict__ sw,
                                            float* __restrict__ out_final,
                                            float* __restrict__ outf,
                                            float* __restrict__ wsw) {
  const int b = blockIdx.x, c = threadIdx.x;
  const float bias = b1[c];
  float s = 0.f, s2 = 0.f;
  const float* xp = x + (size_t)b * BS_BN * D + c;
  for (int r = 0; r < BS_BN; ++r) {
    float v = xp[(size_t)r * D] + bias;
    s += v; s2 = fmaf(v, v, s2);
  }
  float mean = s * (1.f / BS_BN);
  float var = s2 * (1.f / BS_BN) - mean * mean;
  float scale = gamma[c] * rsqrtf(var + 1e-5f);
  float shift = beta[c] - mean * scale;
  float swc = sw[c];
  float* op  = out_final + (size_t)b * BS_BN * D + c;
  float* ofp = outf + (size_t)b * BS_BN * D + c;
  float* wp  = wsw + (size_t)b * BS_BN * D + c;
  for (int r = 0; r < BS_BN; ++r) {
    float v = fmaf(xp[(size_t)r * D] + bias, scale, shift);
    op[(size_t)r * D] = v;
    ofp[(size_t)r * D] = v;
    wp[(size_t)r * D] = v * swc;
  }
}

// ---------------- K2b: a[i] = sum_k sw[k]*out[i,k]^2 (ROUND-1 proven) ----------------
__global__ __launch_bounds__(256) void k_arow(const float* __restrict__ outf,
                                              const float* __restrict__ sw,
                                              float* __restrict__ aarr) {
  const int t = threadIdx.x;
  const int lane = t & 63;
  const int row = blockIdx.x * 4 + (t >> 6);
  float o1 = outf[(size_t)row * D + lane];
  float o2 = outf[(size_t)row * D + 64 + lane];
  float v = sw[lane] * o1 * o1 + sw[64 + lane] * o2 * o2;
#pragma unroll
  for (int off = 32; off >= 1; off >>= 1) v += __shfl_xor(v, off);
  if (lane == 0) aarr[row] = v;
}

// ---------------- K3: scores via split-bf16 MFMA (ROUND-5 proven) ----------------
__global__ __launch_bounds__(256) void k_score(const float* __restrict__ outf,
                                               const float* __restrict__ wsw,
                                               const float* __restrict__ aarr,
                                               const float* __restrict__ sbp,
                                               float* __restrict__ S) {
  __shared__ alignas(16) float Af[128 * 44];
  __shared__ alignas(16) float Bf[128 * 44];
  const int t = threadIdx.x;
  const int lane = t & 63, wid = t >> 6;
  const int q = lane >> 4, l15 = lane & 15;
  const int ib = blockIdx.x * 128, jb = blockIdx.y * 128;
  const int wm = (wid & 1) * 64, wn = (wid >> 1) * 64;

  f32x4 acc[4][4];
#pragma unroll
  for (int mt = 0; mt < 4; ++mt)
#pragma unroll
    for (int nt = 0; nt < 4; ++nt) acc[mt][nt] = (f32x4){0.f, 0.f, 0.f, 0.f};

  for (int kb = 0; kb < D; kb += 32) {
    __syncthreads();
#pragma unroll
    for (int s = 0; s < 4; ++s) {
      int idx = t + 256 * s;
      int row = idx >> 3, f4 = (idx & 7) * 4;
      int gi = ib + row; if (gi > N_TOTAL - 1) gi = N_TOTAL - 1;
      int gj = jb + row; if (gj > N_TOTAL - 1) gj = N_TOTAL - 1;
      *(float4*)&Af[row * 44 + f4] = *(const float4*)&outf[(size_t)gi * D + kb + f4];
      *(float4*)&Bf[row * 44 + f4] = *(const float4*)&wsw[(size_t)gj * D + kb + f4];
    }
    __syncthreads();
    U16 Ah[4], Al[4], Bh[4], Bl[4];
#pragma unroll
    for (int mt = 0; mt < 4; ++mt) {
      int ro = (wm + mt * 16 + l15) * 44 + q * 8;
      float4 x0 = *(const float4*)&Af[ro];
      float4 x1 = *(const float4*)&Af[ro + 4];
      split8(x0, x1, Ah[mt], Al[mt]);
    }
#pragma unroll
    for (int nt = 0; nt < 4; ++nt) {
      int ro = (wn + nt * 16 + l15) * 44 + q * 8;
      float4 x0 = *(const float4*)&Bf[ro];
      float4 x1 = *(const float4*)&Bf[ro + 4];
      split8(x0, x1, Bh[nt], Bl[nt]);
    }
#pragma unroll
    for (int mt = 0; mt < 4; ++mt)
#pragma unroll
      for (int nt = 0; nt < 4; ++nt) {
        acc[mt][nt] = __builtin_amdgcn_mfma_f32_16x16x32_bf16(Ah[mt].b, Bh[nt].b, acc[mt][nt], 0, 0, 0);
        acc[mt][nt] = __builtin_amdgcn_mfma_f32_16x16x32_bf16(Ah[mt].b, Bl[nt].b, acc[mt][nt], 0, 0, 0);
        acc[mt][nt] = __builtin_amdgcn_mfma_f32_16x16x32_bf16(Al[mt].b, Bh[nt].b, acc[mt][nt], 0, 0, 0);
      }
  }

  const float sb = sbp[0];
  float ajv[4];
  int gjc[4];
#pragma unroll
  for (int nt = 0; nt < 4; ++nt) {
    gjc[nt] = jb + wn + nt * 16 + l15;
    ajv[nt] = aarr[gjc[nt] < N_TOTAL ? gjc[nt] : N_TOTAL - 1];
  }
#pragma unroll
  for (int mt = 0; mt < 4; ++mt) {
#pragma unroll
    for (int r = 0; r < 4; ++r) {
      int gi = ib + wm + mt * 16 + q * 4 + r;
      if (gi >= N_TOTAL) continue;
      float ai = aarr[gi] + sb;
#pragma unroll
      for (int nt = 0; nt < 4; ++nt) {
        if (gjc[nt] < N_TOTAL) {
          float s = ai + ajv[nt] - 2.f * acc[mt][nt][r];
          S[(size_t)gi * N_TOTAL + gjc[nt]] = (s > 0.f) ? s : 0.f;  // +0.0 always
        }
      }
    }
  }
}

// ---------------- K5: per-row exact top-50 via exponent-descent + compacted single-wave search ----
// grid 10000, block 256. float4 loads; block binary search replaced by: rowmax ->
// one-exponent descent (count>=C) -> compact <=1024 candidates to LDS -> wave0
// barrier-free binary search. Block-wide fallbacks for dense-bin / all-zero rows.
__global__ __launch_bounds__(256) void k_topk(float* __restrict__ S) {
  const int t = threadIdx.x;
  const int lane = t & 63, wid = t >> 6;
  const size_t rbase = (size_t)blockIdx.x * N_TOTAL;
  const uint4* rp4v = (const uint4*)(S + rbase);

  // load row: 10 x float4 per thread; col(j,e) = (j*256+t)*4+e ; 10000 = 9*1024 + 196*4
  uint v[10][4];
#pragma unroll
  for (int j = 0; j < 10; ++j) {
    if (j < 9 || t < 196) {
      uint4 x = rp4v[j * 256 + t];
      v[j][0] = x.x; v[j][1] = x.y; v[j][2] = x.z; v[j][3] = x.w;
    } else {
      v[j][0] = v[j][1] = v[j][2] = v[j][3] = 0u;  // padding cols >= 10000
    }
  }

  __shared__ uint wred[4];
  __shared__ int scnt;
  __shared__ int ctr;
  __shared__ uint sT;
  __shared__ uint candv[1024];
  __shared__ float topv[TOPK];
  __shared__ int topi[TOPK];

  // ---- rowmax ----
  uint mx = 0u;
#pragma unroll
  for (int j = 0; j < 10; ++j)
#pragma unroll
    for (int e = 0; e < 4; ++e) mx = max(mx, v[j][e]);
#pragma unroll
  for (int off = 32; off >= 1; off >>= 1)
    mx = max(mx, (uint)__shfl_xor((int)mx, off));
  if (lane == 0) wred[wid] = mx;
  __syncthreads();
  mx = max(max(wred[0], wred[1]), max(wred[2], wred[3]));
  __syncthreads();

  uint T = 0u;
  bool zero_path = (mx == 0u);
  if (!zero_path) {
    uint C = mx & 0xFF800000u;
    if (C == 0u) C = 1u;
    uint Chi = mx + 1u;          // exclusive upper bound for T
    int cnt = 0, c_loc = 0;
    for (;;) {
      if (t == 0) scnt = 0;
      __syncthreads();
      c_loc = 0;
#pragma unroll
      for (int j = 0; j < 10; ++j)
#pragma unroll
        for (int e = 0; e < 4; ++e) c_loc += (v[j][e] >= C) ? 1 : 0;
      int cw = c_loc;
#pragma unroll
      for (int off = 32; off >= 1; off >>= 1) cw += __shfl_xor(cw, off);
      if (lane == 0) atomicAdd(&scnt, cw);
      __syncthreads();
      cnt = scnt;
      __syncthreads();
      if (cnt >= TOPK || C == 1u) break;
      Chi = C;                           // count(>=C) < 50  =>  T < C
      C = (C > (1u << 23)) ? (C - (1u << 23)) : 1u;
    }
    if (cnt < TOPK) {
      zero_path = true;                  // fewer than 50 positive scores
    } else if (cnt <= 1024) {
      // compact candidates >= C into LDS (one atomic per thread)
      if (t == 0) ctr = 0;
      __syncthreads();
      int base_ = (c_loc > 0) ? atomicAdd(&ctr, c_loc) : 0;
      int p = base_;
#pragma unroll
      for (int j = 0; j < 10; ++j)
#pragma unroll
        for (int e = 0; e < 4; ++e)
          if (v[j][e] >= C) candv[p++] = v[j][e];
      __syncthreads();
      if (wid == 0) {                    // barrier-free single-wave search
        uint cv[16];
#pragma unroll
        for (int s = 0; s < 16; ++s) {
          int ix = lane + s * 64;
          cv[s] = (ix < cnt) ? candv[ix] : 0u;
        }
        uint L = C, H = Chi;
        while (H - L > 1u) {
          uint M = L + ((H - L) >> 1);
          int cc = 0;
#pragma unroll
          for (int s = 0; s < 16; ++s) cc += (cv[s] >= M) ? 1 : 0;
#pragma unroll
          for (int off = 32; off >= 1; off >>= 1) cc += __shfl_xor(cc, off);
          if (cc >= TOPK) L = M; else H = M;
        }
        if (lane == 0) sT = L;
      }
      __syncthreads();
      T = sT;
    } else {
      // dense exponent bin: block-wide binary search over [C, Chi)
      uint L = C, H = Chi;
      while (H - L > 1u) {
        uint M = L + ((H - L) >> 1);
        if (t == 0) scnt = 0;
        __syncthreads();
        int c = 0;
#pragma unroll
        for (int j = 0; j < 10; ++j)
#pragma unroll
          for (int e = 0; e < 4; ++e) c += (v[j][e] >= M) ? 1 : 0;
#pragma unroll
        for (int off = 32; off >= 1; off >>= 1) c += __shfl_xor(c, off);
        if (lane == 0) atomicAdd(&scnt, c);
        __syncthreads();
        int f = scnt;
        __syncthreads();
        if (f >= TOPK) L = M; else H = M;
      }
      T = L;
    }
  }

  // ---- strict-greater collection (both paths; count(v>T) < 50 by construction) ----
  if (t == 0) ctr = 0;
  __syncthreads();
  int cg = 0;
#pragma unroll
  for (int j = 0; j < 10; ++j)
#pragma unroll
    for (int e = 0; e < 4; ++e) cg += (v[j][e] > T) ? 1 : 0;
  int gbase = (cg > 0) ? atomicAdd(&ctr, cg) : 0;
  {
    int p = gbase;
#pragma unroll
    for (int j = 0; j < 10; ++j)
#pragma unroll
      for (int e = 0; e < 4; ++e)
        if (v[j][e] > T) {
          if (p < TOPK) { topv[p] = __uint_as_float(v[j][e]); topi[p] = (j * 256 + t) * 4 + e; }
          ++p;
        }
  }
  __syncthreads();
  const int cnt_gt = min(ctr, TOPK);
  __syncthreads();
  const int need = TOPK - cnt_gt;

  if (!zero_path) {
    // equals: collect indices (ties tiny for T>0), wave0 picks `need` smallest
    if (t == 0) scnt = 0;
    __syncthreads();
    int ce = 0;
#pragma unroll
    for (int j = 0; j < 10; ++j)
#pragma unroll
      for (int e = 0; e < 4; ++e) ce += (v[j][e] == T) ? 1 : 0;
    int ebase = (ce > 0) ? atomicAdd(&scnt, ce) : 0;
    {
      int p = ebase;
#pragma unroll
      for (int j = 0; j < 10; ++j)
#pragma unroll
        for (int e = 0; e < 4; ++e)
          if (v[j][e] == T) {
            if (p < 1024) candv[p] = (uint)((j * 256 + t) * 4 + e);
            ++p;
          }
    }
    __syncthreads();
    int nE = min(scnt, 1024);
    if (wid == 0) {
      int es[16];
#pragma unroll
      for (int s = 0; s < 16; ++s) {
        int ix = lane + s * 64;
        es[s] = (ix < nE) ? (int)candv[ix] : 0x7FFFFFFF;
      }
      for (int r = 0; r < need; ++r) {
        int m = es[0];
#pragma unroll
        for (int s = 1; s < 16; ++s) m = min(m, es[s]);
#pragma unroll
        for (int off = 32; off >= 1; off >>= 1) m = min(m, __shfl_xor(m, off));
        if (lane == 0 && m != 0x7FFFFFFF) {
          topv[cnt_gt + r] = __uint_as_float(T);
          topi[cnt_gt + r] = m;
        }
#pragma unroll
        for (int s = 0; s < 16; ++s) if (es[s] == m) es[s] = 0x7FFFFFFF;
      }
    }
    __syncthreads();
  } else {
    // T==0: `need` smallest zero-columns via column binary search (exact tiebreak)
    int L = 0, H = N_TOTAL;
    while (H - L > 1) {
      int M = L + ((H - L) >> 1);
      if (t == 0) scnt = 0;
      __syncthreads();
      int c = 0;
#pragma unroll
      for (int j = 0; j < 10; ++j)
#pragma unroll
        for (int e = 0; e < 4; ++e) {
          int col = (j * 256 + t) * 4 + e;
          c += (v[j][e] == 0u && col < M) ? 1 : 0;
        }
#pragma unroll
      for (int off = 32; off >= 1; off >>= 1) c += __shfl_xor(c, off);
      if (lane == 0) atomicAdd(&scnt, c);
      __syncthreads();
      int f = scnt;
      __syncthreads();
      if (f >= need) H = M; else L = M;
    }
    // zeros with col < H are exactly `need` of them
    if (t == 0) scnt = 0;
    __syncthreads();
    int cz = 0;
#pragma unroll
    for (int j = 0; j < 10; ++j)
#pragma unroll
      for (int e = 0; e < 4; ++e) {
        int col = (j * 256 + t) * 4 + e;
        cz += (v[j][e] == 0u && col < H) ? 1 : 0;
      }
    int zbase = (cz > 0) ? atomicAdd(&scnt, cz) : 0;
    {
      int p = zbase;
#pragma unroll
      for (int j = 0; j < 10; ++j)
#pragma unroll
        for (int e = 0; e < 4; ++e) {
          int col = (j * 256 + t) * 4 + e;
          if (v[j][e] == 0u && col < H) {
            if (cnt_gt + p < TOPK) { topv[cnt_gt + p] = 0.0f; topi[cnt_gt + p] = col; }
            ++p;
          }
        }
    }
    __syncthreads();
  }

  // ---- softmax over the 50 (wave 0) ----
  if (wid == 0) {
    float xv = (lane < TOPK) ? topv[lane] : -1e30f;
    float mxf = xv;
#pragma unroll
    for (int off = 32; off >= 1; off >>= 1) mxf = fmaxf(mxf, __shfl_xor(mxf, off));
    float e = (lane < TOPK) ? expf(xv - mxf) : 0.f;
    float ss = e;
#pragma unroll
    for (int off = 32; off >= 1; off >>= 1) ss += __shfl_xor(ss, off);
    if (lane < TOPK) topv[lane] = e / ss;
  }
  __syncthreads();

  // ---- rewrite row: zeros + scatter ----
  float4 z = make_float4(0.f, 0.f, 0.f, 0.f);
  float4* wp4 = (float4*)(S + rbase);
  for (int i = t; i < N_TOTAL / 4; i += 256) wp4[i] = z;
  __syncthreads();
  if (t < TOPK) {
    int ii = topi[t];
    if (ii >= 0 && ii < N_TOTAL) S[rbase + ii] = topv[t];
  }
}

extern "C" void kernel_launch(void* const* d_in, const int* in_sizes, int n_in,
                              void* d_out, int out_size, void* d_ws, size_t ws_size,
                              hipStream_t stream) {
  const float* in    = (const float*)d_in[0];
  const float* W1    = (const float*)d_in[1];
  const float* b1    = (const float*)d_in[2];
  const float* gamma = (const float*)d_in[3];
  const float* beta  = (const float*)d_in[4];
  const float* sw    = (const float*)d_in[5];
  const float* sb    = (const float*)d_in[6];
  float* out_f = (float*)d_out;
  float* S = out_f + (size_t)N_TOTAL * D;  // [10000,10000]

  // ROUND-1 proven ws layout (~15.4 MB)
  float* wsf  = (float*)d_ws;
  float* x    = wsf;                // 1,280,000 f
  float* outf = wsf + 1280000;      // 1,280,000 f
  float* wswb = wsf + 2560000;      // 1,280,000 f
  float* aarr = wsf + 3840000;      // 10,000 f

  hipMemsetAsync(x, 0, (size_t)N_TOTAL * D * sizeof(float), stream);
  k_gemm1<<<dim3(79, 4), 256, 0, stream>>>(in, W1, x);
  k_bn<<<100, 128, 0, stream>>>(x, b1, gamma, beta, sw, out_f, outf, wswb);
  k_arow<<<2500, 256, 0, stream>>>(outf, sw, aarr);
  k_score<<<dim3(79, 79), 256, 0, stream>>>(outf, wswb, aarr, sb, S);
  k_topk<<<10000, 256, 0, stream>>>(S);
}

// Round 7
// 905.166 us; speedup vs baseline: 1.4021x; 1.1374x over previous
//
#include <hip/hip_runtime.h>
#include <cstdint>

#define N_TOTAL 10000
#define D 128
#define FEAT 3072
#define BS_BN 100
#define TOPK 50

typedef unsigned int uint;
typedef short short8 __attribute__((ext_vector_type(8)));
typedef float f32x4 __attribute__((ext_vector_type(4)));
union U16 { uint4 u; short8 b; };

// Split fp32 -> bf16 hi (truncate) + bf16 lo (truncate of residual), 8 at a time.
__device__ inline void split8(float4 f0, float4 f1, U16& h, U16& l) {
  float f[8] = {f0.x, f0.y, f0.z, f0.w, f1.x, f1.y, f1.z, f1.w};
  uint hb[8], lb[8];
#pragma unroll
  for (int e = 0; e < 8; ++e) {
    uint b = __float_as_uint(f[e]);
    uint hx = b & 0xFFFF0000u;
    float lf = f[e] - __uint_as_float(hx);
    hb[e] = b >> 16;
    lb[e] = __float_as_uint(lf) >> 16;
  }
  h.u = make_uint4(hb[0] | (hb[1] << 16), hb[2] | (hb[3] << 16),
                   hb[4] | (hb[5] << 16), hb[6] | (hb[7] << 16));
  l.u = make_uint4(lb[0] | (lb[1] << 16), lb[2] | (lb[3] << 16),
                   lb[4] | (lb[5] << 16), lb[6] | (lb[7] << 16));
}

// ---------------- K1: x = in @ W1^T via split-bf16 MFMA (k_score-clone structure) ----------------
// grid (79, 4), block 256 = 4 waves (2x2 quadrants of 64x64). M-tile 128, N = 128 (all
// W1 channels), K-slice 768 (24 k-steps of 32). fp32 LDS staging + in-register split8,
// 3x mfma per fragment pair; fp32 atomicAdd epilogue into zeroed x (round-1/6-proven).
__global__ __launch_bounds__(256) void k_gemm1(const float* __restrict__ in,
                                               const float* __restrict__ W1,
                                               float* __restrict__ x) {
  __shared__ alignas(16) float Af[128 * 44];  // [row][k] pad 32->44
  __shared__ alignas(16) float Bf[128 * 44];
  const int t = threadIdx.x;
  const int lane = t & 63, wid = t >> 6;
  const int q = lane >> 4, l15 = lane & 15;
  const int i0 = blockIdx.x * 128;
  const int k0 = blockIdx.y * 768;
  const int wm = (wid & 1) * 64, wn = (wid >> 1) * 64;

  f32x4 acc[4][4];
#pragma unroll
  for (int mt = 0; mt < 4; ++mt)
#pragma unroll
    for (int nt = 0; nt < 4; ++nt) acc[mt][nt] = (f32x4){0.f, 0.f, 0.f, 0.f};

  for (int kb = k0; kb < k0 + 768; kb += 32) {
    __syncthreads();
#pragma unroll
    for (int s = 0; s < 4; ++s) {
      int idx = t + 256 * s;               // 1024 float4 slots per matrix
      int row = idx >> 3, f4 = (idx & 7) * 4;
      int gi = i0 + row; if (gi > N_TOTAL - 1) gi = N_TOTAL - 1;
      *(float4*)&Af[row * 44 + f4] = *(const float4*)&in[(size_t)gi * FEAT + kb + f4];
      *(float4*)&Bf[row * 44 + f4] = *(const float4*)&W1[(size_t)row * FEAT + kb + f4];
    }
    __syncthreads();
    U16 Ah[4], Al[4], Bh[4], Bl[4];
#pragma unroll
    for (int mt = 0; mt < 4; ++mt) {
      int ro = (wm + mt * 16 + l15) * 44 + q * 8;
      float4 x0 = *(const float4*)&Af[ro];
      float4 x1 = *(const float4*)&Af[ro + 4];
      split8(x0, x1, Ah[mt], Al[mt]);
    }
#pragma unroll
    for (int nt = 0; nt < 4; ++nt) {
      int ro = (wn + nt * 16 + l15) * 44 + q * 8;
      float4 x0 = *(const float4*)&Bf[ro];
      float4 x1 = *(const float4*)&Bf[ro + 4];
      split8(x0, x1, Bh[nt], Bl[nt]);
    }
#pragma unroll
    for (int mt = 0; mt < 4; ++mt)
#pragma unroll
      for (int nt = 0; nt < 4; ++nt) {
        acc[mt][nt] = __builtin_amdgcn_mfma_f32_16x16x32_bf16(Ah[mt].b, Bh[nt].b, acc[mt][nt], 0, 0, 0);
        acc[mt][nt] = __builtin_amdgcn_mfma_f32_16x16x32_bf16(Ah[mt].b, Bl[nt].b, acc[mt][nt], 0, 0, 0);
        acc[mt][nt] = __builtin_amdgcn_mfma_f32_16x16x32_bf16(Al[mt].b, Bh[nt].b, acc[mt][nt], 0, 0, 0);
      }
  }

  // C layout: row = q*4 + r (within 16), col = l15. atomicAdd accumulates splitK slices.
#pragma unroll
  for (int mt = 0; mt < 4; ++mt) {
#pragma unroll
    for (int r = 0; r < 4; ++r) {
      int gi = i0 + wm + mt * 16 + q * 4 + r;
      if (gi >= N_TOTAL) continue;
#pragma unroll
      for (int nt = 0; nt < 4; ++nt)
        atomicAdd(&x[(size_t)gi * D + wn + nt * 16 + l15], acc[mt][nt][r]);
    }
  }
}

// ---------------- K2: BatchNorm per 100-row batch (ROUND-1 proven) ----------------
__global__ __launch_bounds__(128) void k_bn(const float* __restrict__ x,
                                            const float* __restrict__ b1,
                                            const float* __restrict__ gamma,
                                            const float* __restrict__ beta,
                                            const float* __restrict__ sw,
                                            float* __restrict__ out_final,
                                            float* __restrict__ outf,
                                            float* __restrict__ wsw) {
  const int b = blockIdx.x, c = threadIdx.x;
  const float bias = b1[c];
  float s = 0.f, s2 = 0.f;
  const float* xp = x + (size_t)b * BS_BN * D + c;
  for (int r = 0; r < BS_BN; ++r) {
    float v = xp[(size_t)r * D] + bias;
    s += v; s2 = fmaf(v, v, s2);
  }
  float mean = s * (1.f / BS_BN);
  float var = s2 * (1.f / BS_BN) - mean * mean;
  float scale = gamma[c] * rsqrtf(var + 1e-5f);
  float shift = beta[c] - mean * scale;
  float swc = sw[c];
  float* op  = out_final + (size_t)b * BS_BN * D + c;
  float* ofp = outf + (size_t)b * BS_BN * D + c;
  float* wp  = wsw + (size_t)b * BS_BN * D + c;
  for (int r = 0; r < BS_BN; ++r) {
    float v = fmaf(xp[(size_t)r * D] + bias, scale, shift);
    op[(size_t)r * D] = v;
    ofp[(size_t)r * D] = v;
    wp[(size_t)r * D] = v * swc;
  }
}

// ---------------- K2b: a[i] = sum_k sw[k]*out[i,k]^2 (ROUND-1 proven) ----------------
__global__ __launch_bounds__(256) void k_arow(const float* __restrict__ outf,
                                              const float* __restrict__ sw,
                                              float* __restrict__ aarr) {
  const int t = threadIdx.x;
  const int lane = t & 63;
  const int row = blockIdx.x * 4 + (t >> 6);
  float o1 = outf[(size_t)row * D + lane];
  float o2 = outf[(size_t)row * D + 64 + lane];
  float v = sw[lane] * o1 * o1 + sw[64 + lane] * o2 * o2;
#pragma unroll
  for (int off = 32; off >= 1; off >>= 1) v += __shfl_xor(v, off);
  if (lane == 0) aarr[row] = v;
}

// ---------------- K3: scores via split-bf16 MFMA (ROUND-5 proven) ----------------
__global__ __launch_bounds__(256) void k_score(const float* __restrict__ outf,
                                               const float* __restrict__ wsw,
                                               const float* __restrict__ aarr,
                                               const float* __restrict__ sbp,
                                               float* __restrict__ S) {
  __shared__ alignas(16) float Af[128 * 44];
  __shared__ alignas(16) float Bf[128 * 44];
  const int t = threadIdx.x;
  const int lane = t & 63, wid = t >> 6;
  const int q = lane >> 4, l15 = lane & 15;
  const int ib = blockIdx.x * 128, jb = blockIdx.y * 128;
  const int wm = (wid & 1) * 64, wn = (wid >> 1) * 64;

  f32x4 acc[4][4];
#pragma unroll
  for (int mt = 0; mt < 4; ++mt)
#pragma unroll
    for (int nt = 0; nt < 4; ++nt) acc[mt][nt] = (f32x4){0.f, 0.f, 0.f, 0.f};

  for (int kb = 0; kb < D; kb += 32) {
    __syncthreads();
#pragma unroll
    for (int s = 0; s < 4; ++s) {
      int idx = t + 256 * s;
      int row = idx >> 3, f4 = (idx & 7) * 4;
      int gi = ib + row; if (gi > N_TOTAL - 1) gi = N_TOTAL - 1;
      int gj = jb + row; if (gj > N_TOTAL - 1) gj = N_TOTAL - 1;
      *(float4*)&Af[row * 44 + f4] = *(const float4*)&outf[(size_t)gi * D + kb + f4];
      *(float4*)&Bf[row * 44 + f4] = *(const float4*)&wsw[(size_t)gj * D + kb + f4];
    }
    __syncthreads();
    U16 Ah[4], Al[4], Bh[4], Bl[4];
#pragma unroll
    for (int mt = 0; mt < 4; ++mt) {
      int ro = (wm + mt * 16 + l15) * 44 + q * 8;
      float4 x0 = *(const float4*)&Af[ro];
      float4 x1 = *(const float4*)&Af[ro + 4];
      split8(x0, x1, Ah[mt], Al[mt]);
    }
#pragma unroll
    for (int nt = 0; nt < 4; ++nt) {
      int ro = (wn + nt * 16 + l15) * 44 + q * 8;
      float4 x0 = *(const float4*)&Bf[ro];
      float4 x1 = *(const float4*)&Bf[ro + 4];
      split8(x0, x1, Bh[nt], Bl[nt]);
    }
#pragma unroll
    for (int mt = 0; mt < 4; ++mt)
#pragma unroll
      for (int nt = 0; nt < 4; ++nt) {
        acc[mt][nt] = __builtin_amdgcn_mfma_f32_16x16x32_bf16(Ah[mt].b, Bh[nt].b, acc[mt][nt], 0, 0, 0);
        acc[mt][nt] = __builtin_amdgcn_mfma_f32_16x16x32_bf16(Ah[mt].b, Bl[nt].b, acc[mt][nt], 0, 0, 0);
        acc[mt][nt] = __builtin_amdgcn_mfma_f32_16x16x32_bf16(Al[mt].b, Bh[nt].b, acc[mt][nt], 0, 0, 0);
      }
  }

  const float sb = sbp[0];
  float ajv[4];
  int gjc[4];
#pragma unroll
  for (int nt = 0; nt < 4; ++nt) {
    gjc[nt] = jb + wn + nt * 16 + l15;
    ajv[nt] = aarr[gjc[nt] < N_TOTAL ? gjc[nt] : N_TOTAL - 1];
  }
#pragma unroll
  for (int mt = 0; mt < 4; ++mt) {
#pragma unroll
    for (int r = 0; r < 4; ++r) {
      int gi = ib + wm + mt * 16 + q * 4 + r;
      if (gi >= N_TOTAL) continue;
      float ai = aarr[gi] + sb;
#pragma unroll
      for (int nt = 0; nt < 4; ++nt) {
        if (gjc[nt] < N_TOTAL) {
          float s = ai + ajv[nt] - 2.f * acc[mt][nt][r];
          S[(size_t)gi * N_TOTAL + gjc[nt]] = (s > 0.f) ? s : 0.f;  // +0.0 always
        }
      }
    }
  }
}

// ---------------- K5: per-row exact top-50 (ROUND-6 proven) ----------------
__global__ __launch_bounds__(256) void k_topk(float* __restrict__ S) {
  const int t = threadIdx.x;
  const int lane = t & 63, wid = t >> 6;
  const size_t rbase = (size_t)blockIdx.x * N_TOTAL;
  const uint4* rp4v = (const uint4*)(S + rbase);

  uint v[10][4];
#pragma unroll
  for (int j = 0; j < 10; ++j) {
    if (j < 9 || t < 196) {
      uint4 x = rp4v[j * 256 + t];
      v[j][0] = x.x; v[j][1] = x.y; v[j][2] = x.z; v[j][3] = x.w;
    } else {
      v[j][0] = v[j][1] = v[j][2] = v[j][3] = 0u;
    }
  }

  __shared__ uint wred[4];
  __shared__ int scnt;
  __shared__ int ctr;
  __shared__ uint sT;
  __shared__ uint candv[1024];
  __shared__ float topv[TOPK];
  __shared__ int topi[TOPK];

  uint mx = 0u;
#pragma unroll
  for (int j = 0; j < 10; ++j)
#pragma unroll
    for (int e = 0; e < 4; ++e) mx = max(mx, v[j][e]);
#pragma unroll
  for (int off = 32; off >= 1; off >>= 1)
    mx = max(mx, (uint)__shfl_xor((int)mx, off));
  if (lane == 0) wred[wid] = mx;
  __syncthreads();
  mx = max(max(wred[0], wred[1]), max(wred[2], wred[3]));
  __syncthreads();

  uint T = 0u;
  bool zero_path = (mx == 0u);
  if (!zero_path) {
    uint C = mx & 0xFF800000u;
    if (C == 0u) C = 1u;
    uint Chi = mx + 1u;
    int cnt = 0, c_loc = 0;
    for (;;) {
      if (t == 0) scnt = 0;
      __syncthreads();
      c_loc = 0;
#pragma unroll
      for (int j = 0; j < 10; ++j)
#pragma unroll
        for (int e = 0; e < 4; ++e) c_loc += (v[j][e] >= C) ? 1 : 0;
      int cw = c_loc;
#pragma unroll
      for (int off = 32; off >= 1; off >>= 1) cw += __shfl_xor(cw, off);
      if (lane == 0) atomicAdd(&scnt, cw);
      __syncthreads();
      cnt = scnt;
      __syncthreads();
      if (cnt >= TOPK || C == 1u) break;
      Chi = C;
      C = (C > (1u << 23)) ? (C - (1u << 23)) : 1u;
    }
    if (cnt < TOPK) {
      zero_path = true;
    } else if (cnt <= 1024) {
      if (t == 0) ctr = 0;
      __syncthreads();
      int base_ = (c_loc > 0) ? atomicAdd(&ctr, c_loc) : 0;
      int p = base_;
#pragma unroll
      for (int j = 0; j < 10; ++j)
#pragma unroll
        for (int e = 0; e < 4; ++e)
          if (v[j][e] >= C) candv[p++] = v[j][e];
      __syncthreads();
      if (wid == 0) {
        uint cv[16];
#pragma unroll
        for (int s = 0; s < 16; ++s) {
          int ix = lane + s * 64;
          cv[s] = (ix < cnt) ? candv[ix] : 0u;
        }
        uint L = C, H = Chi;
        while (H - L > 1u) {
          uint M = L + ((H - L) >> 1);
          int cc = 0;
#pragma unroll
          for (int s = 0; s < 16; ++s) cc += (cv[s] >= M) ? 1 : 0;
#pragma unroll
          for (int off = 32; off >= 1; off >>= 1) cc += __shfl_xor(cc, off);
          if (cc >= TOPK) L = M; else H = M;
        }
        if (lane == 0) sT = L;
      }
      __syncthreads();
      T = sT;
    } else {
      uint L = C, H = Chi;
      while (H - L > 1u) {
        uint M = L + ((H - L) >> 1);
        if (t == 0) scnt = 0;
        __syncthreads();
        int c = 0;
#pragma unroll
        for (int j = 0; j < 10; ++j)
#pragma unroll
          for (int e = 0; e < 4; ++e) c += (v[j][e] >= M) ? 1 : 0;
#pragma unroll
        for (int off = 32; off >= 1; off >>= 1) c += __shfl_xor(c, off);
        if (lane == 0) atomicAdd(&scnt, c);
        __syncthreads();
        int f = scnt;
        __syncthreads();
        if (f >= TOPK) L = M; else H = M;
      }
      T = L;
    }
  }

  if (t == 0) ctr = 0;
  __syncthreads();
  int cg = 0;
#pragma unroll
  for (int j = 0; j < 10; ++j)
#pragma unroll
    for (int e = 0; e < 4; ++e) cg += (v[j][e] > T) ? 1 : 0;
  int gbase = (cg > 0) ? atomicAdd(&ctr, cg) : 0;
  {
    int p = gbase;
#pragma unroll
    for (int j = 0; j < 10; ++j)
#pragma unroll
      for (int e = 0; e < 4; ++e)
        if (v[j][e] > T) {
          if (p < TOPK) { topv[p] = __uint_as_float(v[j][e]); topi[p] = (j * 256 + t) * 4 + e; }
          ++p;
        }
  }
  __syncthreads();
  const int cnt_gt = min(ctr, TOPK);
  __syncthreads();
  const int need = TOPK - cnt_gt;

  if (!zero_path) {
    if (t == 0) scnt = 0;
    __syncthreads();
    int ce = 0;
#pragma unroll
    for (int j = 0; j < 10; ++j)
#pragma unroll
      for (int e = 0; e < 4; ++e) ce += (v[j][e] == T) ? 1 : 0;
    int ebase = (ce > 0) ? atomicAdd(&scnt, ce) : 0;
    {
      int p = ebase;
#pragma unroll
      for (int j = 0; j < 10; ++j)
#pragma unroll
        for (int e = 0; e < 4; ++e)
          if (v[j][e] == T) {
            if (p < 1024) candv[p] = (uint)((j * 256 + t) * 4 + e);
            ++p;
          }
    }
    __syncthreads();
    int nE = min(scnt, 1024);
    if (wid == 0) {
      int es[16];
#pragma unroll
      for (int s = 0; s < 16; ++s) {
        int ix = lane + s * 64;
        es[s] = (ix < nE) ? (int)candv[ix] : 0x7FFFFFFF;
      }
      for (int r = 0; r < need; ++r) {
        int m = es[0];
#pragma unroll
        for (int s = 1; s < 16; ++s) m = min(m, es[s]);
#pragma unroll
        for (int off = 32; off >= 1; off >>= 1) m = min(m, __shfl_xor(m, off));
        if (lane == 0 && m != 0x7FFFFFFF) {
          topv[cnt_gt + r] = __uint_as_float(T);
          topi[cnt_gt + r] = m;
        }
#pragma unroll
        for (int s = 0; s < 16; ++s) if (es[s] == m) es[s] = 0x7FFFFFFF;
      }
    }
    __syncthreads();
  } else {
    int L = 0, H = N_TOTAL;
    while (H - L > 1) {
      int M = L + ((H - L) >> 1);
      if (t == 0) scnt = 0;
      __syncthreads();
      int c = 0;
#pragma unroll
      for (int j = 0; j < 10; ++j)
#pragma unroll
        for (int e = 0; e < 4; ++e) {
          int col = (j * 256 + t) * 4 + e;
          c += (v[j][e] == 0u && col < M) ? 1 : 0;
        }
#pragma unroll
      for (int off = 32; off >= 1; off >>= 1) c += __shfl_xor(c, off);
      if (lane == 0) atomicAdd(&scnt, c);
      __syncthreads();
      int f = scnt;
      __syncthreads();
      if (f >= need) H = M; else L = M;
    }
    if (t == 0) scnt = 0;
    __syncthreads();
    int cz = 0;
#pragma unroll
    for (int j = 0; j < 10; ++j)
#pragma unroll
      for (int e = 0; e < 4; ++e) {
        int col = (j * 256 + t) * 4 + e;
        cz += (v[j][e] == 0u && col < H) ? 1 : 0;
      }
    int zbase = (cz > 0) ? atomicAdd(&scnt, cz) : 0;
    {
      int p = zbase;
#pragma unroll
      for (int j = 0; j < 10; ++j)
#pragma unroll
        for (int e = 0; e < 4; ++e) {
          int col = (j * 256 + t) * 4 + e;
          if (v[j][e] == 0u && col < H) {
            if (cnt_gt + p < TOPK) { topv[cnt_gt + p] = 0.0f; topi[cnt_gt + p] = col; }
            ++p;
          }
        }
    }
    __syncthreads();
  }

  if (wid == 0) {
    float xv = (lane < TOPK) ? topv[lane] : -1e30f;
    float mxf = xv;
#pragma unroll
    for (int off = 32; off >= 1; off >>= 1) mxf = fmaxf(mxf, __shfl_xor(mxf, off));
    float e = (lane < TOPK) ? expf(xv - mxf) : 0.f;
    float ss = e;
#pragma unroll
    for (int off = 32; off >= 1; off >>= 1) ss += __shfl_xor(ss, off);
    if (lane < TOPK) topv[lane] = e / ss;
  }
  __syncthreads();

  float4 z = make_float4(0.f, 0.f, 0.f, 0.f);
  float4* wp4 = (float4*)(S + rbase);
  for (int i = t; i < N_TOTAL / 4; i += 256) wp4[i] = z;
  __syncthreads();
  if (t < TOPK) {
    int ii = topi[t];
    if (ii >= 0 && ii < N_TOTAL) S[rbase + ii] = topv[t];
  }
}

extern "C" void kernel_launch(void* const* d_in, const int* in_sizes, int n_in,
                              void* d_out, int out_size, void* d_ws, size_t ws_size,
                              hipStream_t stream) {
  const float* in    = (const float*)d_in[0];
  const float* W1    = (const float*)d_in[1];
  const float* b1    = (const float*)d_in[2];
  const float* gamma = (const float*)d_in[3];
  const float* beta  = (const float*)d_in[4];
  const float* sw    = (const float*)d_in[5];
  const float* sb    = (const float*)d_in[6];
  float* out_f = (float*)d_out;
  float* S = out_f + (size_t)N_TOTAL * D;  // [10000,10000]

  // ROUND-1 proven ws layout (~15.4 MB)
  float* wsf  = (float*)d_ws;
  float* x    = wsf;                // 1,280,000 f
  float* outf = wsf + 1280000;      // 1,280,000 f
  float* wswb = wsf + 2560000;      // 1,280,000 f
  float* aarr = wsf + 3840000;      // 10,000 f

  hipMemsetAsync(x, 0, (size_t)N_TOTAL * D * sizeof(float), stream);
  k_gemm1<<<dim3(79, 4), 256, 0, stream>>>(in, W1, x);
  k_bn<<<100, 128, 0, stream>>>(x, b1, gamma, beta, sw, out_f, outf, wswb);
  k_arow<<<2500, 256, 0, stream>>>(outf, sw, aarr);
  k_score<<<dim3(79, 79), 256, 0, stream>>>(outf, wswb, aarr, sb, S);
  k_topk<<<10000, 256, 0, stream>>>(S);
}